// Round 3
// baseline (4027.197 us; speedup 1.0000x reference)
//
#include <hip/hip_runtime.h>

typedef unsigned int u32;

__device__ __forceinline__ u32 encf(float f){ u32 u=__float_as_uint(f); return (u&0x80000000u)? ~u : (u|0x80000000u); }
__device__ __forceinline__ float decf(u32 u){ return (u&0x80000000u)? __uint_as_float(u&0x7fffffffu) : __uint_as_float(~u); }

__device__ __forceinline__ float fast_tanh(float x){
  x = fminf(fmaxf(x, -15.f), 15.f);
  float e = __expf(2.f*x);
  return (e - 1.f) * __builtin_amdgcn_rcpf(e + 1.f);
}
__device__ __forceinline__ float fast_sigmoid(float x){
  x = fminf(fmaxf(x, -15.f), 15.f);
  return __builtin_amdgcn_rcpf(1.f + __expf(-x));
}

// Base-voxel index, bit-exact with reference: idx = floor(points + 1.0f); ix = idx-1.
// (points+1 can round UP across an integer; floor(points) alone is WRONG for
//  ~4ppm of points — caused round-2's 0.2266 absmax.)
__device__ __forceinline__ int base_ix(float p){
  return (int)floorf(p + 1.0f) - 1;   // guaranteed in [0,254] for p in [0,255)
}

// ---- pass 1: exact max over gathered channel-7 values -----------------------
__global__ __launch_bounds__(256) void kmax(const float* __restrict__ pts,
                                            const float* __restrict__ g7,
                                            u32* __restrict__ wmax, int n){
  float m = -3.0e38f;
  for (int i = blockIdx.x*blockDim.x + threadIdx.x; i < n; i += gridDim.x*blockDim.x){
    int ix = base_ix(pts[3*i]);
    int iy = base_ix(pts[3*i+1]);
    int iz = base_ix(pts[3*i+2]);
    int xs[3] = {max(ix-1,0), ix, min(ix+1,255)};
    int ys[3] = {max(iy-1,0), iy, min(iy+1,255)};
    int zs[3] = {max(iz-1,0), iz, min(iz+1,255)};
    #pragma unroll
    for (int a=0;a<3;a++)
    #pragma unroll
    for (int b=0;b<3;b++){
      u32 rb = ((u32)xs[a]<<16) | ((u32)ys[b]<<8);
      #pragma unroll
      for (int d=0;d<3;d++) m = fmaxf(m, g7[rb + (u32)zs[d]]);
    }
  }
  #pragma unroll
  for (int o=32;o>=1;o>>=1) m = fmaxf(m, __shfl_xor(m, o));
  if ((threadIdx.x & 63)==0) atomicMax(wmax, encf(m));
}

// ---- pass 2: gather + MLP, one thread per point -----------------------------
__global__ __launch_bounds__(256) void kmain(const float* __restrict__ pts,
                                             const float* __restrict__ g,
                                             const u32* __restrict__ wmax,
                                             float2* __restrict__ out, int n,
                                             const float* __restrict__ Wc, const float* __restrict__ bc,
                                             const float* __restrict__ W1, const float* __restrict__ b1,
                                             const float* __restrict__ W2, const float* __restrict__ b2,
                                             const float* __restrict__ W3, const float* __restrict__ b3,
                                             const float* __restrict__ W4, const float* __restrict__ b4,
                                             const float* __restrict__ Ws, const float* __restrict__ bs,
                                             const float* __restrict__ Wo, const float* __restrict__ bo)
{
  int i = blockIdx.x*256 + threadIdx.x;
  if (i >= n) return;
  float inv = 1.0f / (decf(*wmax) + 1e-9f);

  int ix = base_ix(pts[3*i]);
  int iy = base_ix(pts[3*i+1]);
  int iz = base_ix(pts[3*i+2]);
  int xs[3] = {max(ix-1,0), ix, min(ix+1,255)};
  int ys[3] = {max(iy-1,0), iy, min(iy+1,255)};
  int zs[3] = {max(iz-1,0), iz, min(iz+1,255)};

  u32 cb = ((u32)ix<<16) | ((u32)iy<<8) | (u32)iz;
  float cen[8];
  #pragma unroll
  for (int c=0;c<8;c++) cen[c] = g[((u32)c<<24) + cb];
  cen[7] *= inv;

  float acc[8];
  #pragma unroll
  for (int j=0;j<8;j++) acc[j] = bc[j];

  #pragma unroll
  for (int a=0;a<3;a++)
  #pragma unroll
  for (int b=0;b<3;b++)
  #pragma unroll
  for (int d=0;d<3;d++){
    const int kk = (a*3+b)*3+d;
    u32 vb = ((u32)xs[a]<<16) | ((u32)ys[b]<<8) | (u32)zs[d];
    float v[8];
    #pragma unroll
    for (int c=0;c<8;c++) v[c] = g[((u32)c<<24) + vb];
    v[7] *= inv;
    #pragma unroll
    for (int c=0;c<8;c++)
      #pragma unroll
      for (int j=0;j<8;j++)
        acc[j] = fmaf(v[c], Wc[(kk*8+c)*8 + j], acc[j]);
  }

  // layernorm + tanh -> ctx
  float mean = 0.f;
  #pragma unroll
  for (int j=0;j<8;j++) mean += acc[j];
  mean *= 0.125f;
  float var = 0.f;
  #pragma unroll
  for (int j=0;j<8;j++){ float t = acc[j]-mean; var += t*t; }
  var *= 0.125f;
  float rs = rsqrtf(var + 1e-5f);
  float ctx[8];
  #pragma unroll
  for (int j=0;j<8;j++) ctx[j] = fast_tanh((acc[j]-mean)*rs);

  float h1[32];
  #pragma unroll
  for (int j=0;j<32;j++){
    float s = b1[j];
    #pragma unroll
    for (int c=0;c<8;c++) s = fmaf(cen[c], W1[c*32 + j], s);
    #pragma unroll
    for (int c=0;c<8;c++) s = fmaf(ctx[c], W1[(8+c)*32 + j], s);
    h1[j] = fast_tanh(s);
  }
  float h2[16];
  #pragma unroll
  for (int j=0;j<16;j++){
    float s = b2[j];
    #pragma unroll
    for (int c=0;c<8;c++) s = fmaf(cen[c], W2[c*16 + j], s);
    #pragma unroll
    for (int c=0;c<32;c++) s = fmaf(h1[c], W2[(8+c)*16 + j], s);
    h2[j] = fast_tanh(s);
  }
  float h3[8];
  #pragma unroll
  for (int j=0;j<8;j++){
    float s = b3[j];
    #pragma unroll
    for (int c=0;c<8;c++) s = fmaf(cen[c], W3[c*8 + j], s);
    #pragma unroll
    for (int c=0;c<16;c++) s = fmaf(h2[c], W3[(8+c)*8 + j], s);
    h3[j] = fast_tanh(s);
  }
  float h4[8];
  #pragma unroll
  for (int j=0;j<8;j++){
    float s = b4[j];
    #pragma unroll
    for (int c=0;c<8;c++) s = fmaf(cen[c], W4[c*8 + j], s);
    #pragma unroll
    for (int c=0;c<8;c++) s = fmaf(h3[c], W4[(8+c)*8 + j], s);
    h4[j] = fast_tanh(s);
  }
  float ssdf = bs[0];
  float socc = bo[0];
  #pragma unroll
  for (int c=0;c<8;c++){
    ssdf = fmaf(h4[c], Ws[c], ssdf);
    socc = fmaf(h4[c], Wo[c], socc);
  }
  out[i] = make_float2(fast_tanh(ssdf), fast_sigmoid(socc));
}

extern "C" void kernel_launch(void* const* d_in, const int* in_sizes, int n_in,
                              void* d_out, int out_size, void* d_ws, size_t ws_size,
                              hipStream_t stream)
{
  const float* pts  = (const float*)d_in[0];
  const float* grid = (const float*)d_in[1];
  int n = in_sizes[0] / 3;

  u32* wmax = (u32*)d_ws;
  hipMemsetAsync(d_ws, 0, 64, stream);

  kmax<<<2048, 256, 0, stream>>>(pts, grid + ((size_t)7<<24), wmax, n);

  kmain<<<(n+255)/256, 256, 0, stream>>>(pts, grid, wmax, (float2*)d_out, n,
      (const float*)d_in[2],  (const float*)d_in[3],
      (const float*)d_in[4],  (const float*)d_in[5],
      (const float*)d_in[6],  (const float*)d_in[7],
      (const float*)d_in[8],  (const float*)d_in[9],
      (const float*)d_in[10], (const float*)d_in[11],
      (const float*)d_in[12], (const float*)d_in[13],
      (const float*)d_in[14], (const float*)d_in[15]);
}

// Round 4
// 774.930 us; speedup vs baseline: 5.1968x; 5.1968x over previous
//
#include <hip/hip_runtime.h>

typedef unsigned int u32;

__device__ __forceinline__ u32 encf(float f){ u32 u=__float_as_uint(f); return (u&0x80000000u)? ~u : (u|0x80000000u); }
__device__ __forceinline__ float decf(u32 u){ return (u&0x80000000u)? __uint_as_float(u&0x7fffffffu) : __uint_as_float(~u); }

__device__ __forceinline__ float fast_tanh(float x){
  x = fminf(fmaxf(x, -15.f), 15.f);
  float e = __expf(2.f*x);
  return (e - 1.f) * __builtin_amdgcn_rcpf(e + 1.f);
}
__device__ __forceinline__ float fast_sigmoid(float x){
  x = fminf(fmaxf(x, -15.f), 15.f);
  return __builtin_amdgcn_rcpf(1.f + __expf(-x));
}

// Base-voxel index, bit-exact with reference: idx = floor(points + 1.0f); ix = idx-1.
__device__ __forceinline__ int base_ix(float p){
  return (int)floorf(p + 1.0f) - 1;   // in [0,254] for p in [0,255)
}

// ---- repack: channel-major [8][256^3] -> voxel-major [256^3][8] (32B/voxel) --
__global__ __launch_bounds__(256) void repack(const float* __restrict__ g,
                                              float4* __restrict__ rg){
  u32 v = blockIdx.x*256u + threadIdx.x;   // 65536 blocks x 256 = 16.7M voxels
  float4 lo, hi;
  lo.x = g[(0u<<24)+v]; lo.y = g[(1u<<24)+v]; lo.z = g[(2u<<24)+v]; lo.w = g[(3u<<24)+v];
  hi.x = g[(4u<<24)+v]; hi.y = g[(5u<<24)+v]; hi.z = g[(6u<<24)+v]; hi.w = g[(7u<<24)+v];
  rg[(size_t)v*2]   = lo;
  rg[(size_t)v*2+1] = hi;
}

// ---- pass 1: exact max over gathered channel-7 values (original slab) -------
__global__ __launch_bounds__(256) void kmax(const float* __restrict__ pts,
                                            const float* __restrict__ g7,
                                            u32* __restrict__ wmax, int n){
  float m = -3.0e38f;
  for (int i = blockIdx.x*blockDim.x + threadIdx.x; i < n; i += gridDim.x*blockDim.x){
    int ix = base_ix(pts[3*i]);
    int iy = base_ix(pts[3*i+1]);
    int iz = base_ix(pts[3*i+2]);
    int xs[3] = {max(ix-1,0), ix, min(ix+1,255)};
    int ys[3] = {max(iy-1,0), iy, min(iy+1,255)};
    int zs[3] = {max(iz-1,0), iz, min(iz+1,255)};
    #pragma unroll
    for (int a=0;a<3;a++)
    #pragma unroll
    for (int b=0;b<3;b++){
      u32 rb = ((u32)xs[a]<<16) | ((u32)ys[b]<<8);
      #pragma unroll
      for (int d=0;d<3;d++) m = fmaxf(m, g7[rb + (u32)zs[d]]);
    }
  }
  #pragma unroll
  for (int o=32;o>=1;o>>=1) m = fmaxf(m, __shfl_xor(m, o));
  if ((threadIdx.x & 63)==0) atomicMax(wmax, encf(m));
}

// ================= shared MLP tail (identical math both paths) ===============
__device__ __forceinline__ void mlp_tail(const float* __restrict__ cen,
                                         const float* __restrict__ acc0,
                                         float2* __restrict__ out, int i,
                                         const float* __restrict__ W1, const float* __restrict__ b1,
                                         const float* __restrict__ W2, const float* __restrict__ b2,
                                         const float* __restrict__ W3, const float* __restrict__ b3,
                                         const float* __restrict__ W4, const float* __restrict__ b4,
                                         const float* __restrict__ Ws, const float* __restrict__ bs,
                                         const float* __restrict__ Wo, const float* __restrict__ bo)
{
  float mean = 0.f;
  #pragma unroll
  for (int j=0;j<8;j++) mean += acc0[j];
  mean *= 0.125f;
  float var = 0.f;
  #pragma unroll
  for (int j=0;j<8;j++){ float t = acc0[j]-mean; var += t*t; }
  var *= 0.125f;
  float rs = rsqrtf(var + 1e-5f);
  float ctx[8];
  #pragma unroll
  for (int j=0;j<8;j++) ctx[j] = fast_tanh((acc0[j]-mean)*rs);

  float h1[32];
  #pragma unroll
  for (int j=0;j<32;j++){
    float s = b1[j];
    #pragma unroll
    for (int c=0;c<8;c++) s = fmaf(cen[c], W1[c*32 + j], s);
    #pragma unroll
    for (int c=0;c<8;c++) s = fmaf(ctx[c], W1[(8+c)*32 + j], s);
    h1[j] = fast_tanh(s);
  }
  float h2[16];
  #pragma unroll
  for (int j=0;j<16;j++){
    float s = b2[j];
    #pragma unroll
    for (int c=0;c<8;c++) s = fmaf(cen[c], W2[c*16 + j], s);
    #pragma unroll
    for (int c=0;c<32;c++) s = fmaf(h1[c], W2[(8+c)*16 + j], s);
    h2[j] = fast_tanh(s);
  }
  float h3[8];
  #pragma unroll
  for (int j=0;j<8;j++){
    float s = b3[j];
    #pragma unroll
    for (int c=0;c<8;c++) s = fmaf(cen[c], W3[c*8 + j], s);
    #pragma unroll
    for (int c=0;c<16;c++) s = fmaf(h2[c], W3[(8+c)*8 + j], s);
    h3[j] = fast_tanh(s);
  }
  float h4[8];
  #pragma unroll
  for (int j=0;j<8;j++){
    float s = b4[j];
    #pragma unroll
    for (int c=0;c<8;c++) s = fmaf(cen[c], W4[c*8 + j], s);
    #pragma unroll
    for (int c=0;c<8;c++) s = fmaf(h3[c], W4[(8+c)*8 + j], s);
    h4[j] = fast_tanh(s);
  }
  float ssdf = bs[0];
  float socc = bo[0];
  #pragma unroll
  for (int c=0;c<8;c++){
    ssdf = fmaf(h4[c], Ws[c], ssdf);
    socc = fmaf(h4[c], Wo[c], socc);
  }
  out[i] = make_float2(fast_tanh(ssdf), fast_sigmoid(socc));
}

// ---- pass 2 (fast path): gather from voxel-major repack ---------------------
__global__ __launch_bounds__(256) void kmain_rg(const float* __restrict__ pts,
                                               const float4* __restrict__ rg,
                                               const u32* __restrict__ wmax,
                                               float2* __restrict__ out, int n,
                                               const float* __restrict__ Wc, const float* __restrict__ bc,
                                               const float* __restrict__ W1, const float* __restrict__ b1,
                                               const float* __restrict__ W2, const float* __restrict__ b2,
                                               const float* __restrict__ W3, const float* __restrict__ b3,
                                               const float* __restrict__ W4, const float* __restrict__ b4,
                                               const float* __restrict__ Ws, const float* __restrict__ bs,
                                               const float* __restrict__ Wo, const float* __restrict__ bo)
{
  int i = blockIdx.x*256 + threadIdx.x;
  if (i >= n) return;
  float inv = 1.0f / (decf(*wmax) + 1e-9f);

  int ix = base_ix(pts[3*i]);
  int iy = base_ix(pts[3*i+1]);
  int iz = base_ix(pts[3*i+2]);
  int xs[3] = {max(ix-1,0), ix, min(ix+1,255)};
  int ys[3] = {max(iy-1,0), iy, min(iy+1,255)};
  int zs[3] = {max(iz-1,0), iz, min(iz+1,255)};

  float cen[8];
  float acc[8];
  #pragma unroll
  for (int j=0;j<8;j++) acc[j] = bc[j];

  #pragma unroll
  for (int a=0;a<3;a++)
  #pragma unroll
  for (int b=0;b<3;b++)
  #pragma unroll
  for (int d=0;d<3;d++){
    const int kk = (a*3+b)*3+d;
    u32 vb = ((u32)xs[a]<<16) | ((u32)ys[b]<<8) | (u32)zs[d];
    float4 lo = rg[(size_t)vb*2];
    float4 hi = rg[(size_t)vb*2+1];
    float v[8] = {lo.x,lo.y,lo.z,lo.w, hi.x,hi.y,hi.z, hi.w*inv};
    if (kk == 13){
      #pragma unroll
      for (int c=0;c<8;c++) cen[c] = v[c];
    }
    #pragma unroll
    for (int c=0;c<8;c++)
      #pragma unroll
      for (int j=0;j<8;j++)
        acc[j] = fmaf(v[c], Wc[(kk*8+c)*8 + j], acc[j]);
  }

  mlp_tail(cen, acc, out, i, W1,b1,W2,b2,W3,b3,W4,b4,Ws,bs,Wo,bo);
}

// ---- pass 2 (fallback): direct channel-major gather (round-3 path) ----------
__global__ __launch_bounds__(256) void kmain_direct(const float* __restrict__ pts,
                                                    const float* __restrict__ g,
                                                    const u32* __restrict__ wmax,
                                                    float2* __restrict__ out, int n,
                                                    const float* __restrict__ Wc, const float* __restrict__ bc,
                                                    const float* __restrict__ W1, const float* __restrict__ b1,
                                                    const float* __restrict__ W2, const float* __restrict__ b2,
                                                    const float* __restrict__ W3, const float* __restrict__ b3,
                                                    const float* __restrict__ W4, const float* __restrict__ b4,
                                                    const float* __restrict__ Ws, const float* __restrict__ bs,
                                                    const float* __restrict__ Wo, const float* __restrict__ bo)
{
  int i = blockIdx.x*256 + threadIdx.x;
  if (i >= n) return;
  float inv = 1.0f / (decf(*wmax) + 1e-9f);

  int ix = base_ix(pts[3*i]);
  int iy = base_ix(pts[3*i+1]);
  int iz = base_ix(pts[3*i+2]);
  int xs[3] = {max(ix-1,0), ix, min(ix+1,255)};
  int ys[3] = {max(iy-1,0), iy, min(iy+1,255)};
  int zs[3] = {max(iz-1,0), iz, min(iz+1,255)};

  u32 cb = ((u32)ix<<16) | ((u32)iy<<8) | (u32)iz;
  float cen[8];
  #pragma unroll
  for (int c=0;c<8;c++) cen[c] = g[((u32)c<<24) + cb];
  cen[7] *= inv;

  float acc[8];
  #pragma unroll
  for (int j=0;j<8;j++) acc[j] = bc[j];

  #pragma unroll
  for (int a=0;a<3;a++)
  #pragma unroll
  for (int b=0;b<3;b++)
  #pragma unroll
  for (int d=0;d<3;d++){
    const int kk = (a*3+b)*3+d;
    u32 vb = ((u32)xs[a]<<16) | ((u32)ys[b]<<8) | (u32)zs[d];
    float v[8];
    #pragma unroll
    for (int c=0;c<8;c++) v[c] = g[((u32)c<<24) + vb];
    v[7] *= inv;
    #pragma unroll
    for (int c=0;c<8;c++)
      #pragma unroll
      for (int j=0;j<8;j++)
        acc[j] = fmaf(v[c], Wc[(kk*8+c)*8 + j], acc[j]);
  }

  mlp_tail(cen, acc, out, i, W1,b1,W2,b2,W3,b3,W4,b4,Ws,bs,Wo,bo);
}

extern "C" void kernel_launch(void* const* d_in, const int* in_sizes, int n_in,
                              void* d_out, int out_size, void* d_ws, size_t ws_size,
                              hipStream_t stream)
{
  const float* pts  = (const float*)d_in[0];
  const float* grid = (const float*)d_in[1];
  int n = in_sizes[0] / 3;

  const size_t RG_BYTES = (size_t)16777216 * 32;   // 512 MiB voxel-major copy

  if (ws_size >= RG_BYTES + 64){
    float4* rg  = (float4*)d_ws;
    u32* wmax   = (u32*)((char*)d_ws + RG_BYTES);
    hipMemsetAsync(wmax, 0, 64, stream);
    repack<<<65536, 256, 0, stream>>>(grid, rg);
    kmax<<<2048, 256, 0, stream>>>(pts, grid + ((size_t)7<<24), wmax, n);
    kmain_rg<<<(n+255)/256, 256, 0, stream>>>(pts, rg, wmax, (float2*)d_out, n,
        (const float*)d_in[2],  (const float*)d_in[3],
        (const float*)d_in[4],  (const float*)d_in[5],
        (const float*)d_in[6],  (const float*)d_in[7],
        (const float*)d_in[8],  (const float*)d_in[9],
        (const float*)d_in[10], (const float*)d_in[11],
        (const float*)d_in[12], (const float*)d_in[13],
        (const float*)d_in[14], (const float*)d_in[15]);
  } else {
    u32* wmax = (u32*)d_ws;
    hipMemsetAsync(wmax, 0, 64, stream);
    kmax<<<2048, 256, 0, stream>>>(pts, grid + ((size_t)7<<24), wmax, n);
    kmain_direct<<<(n+255)/256, 256, 0, stream>>>(pts, grid, wmax, (float2*)d_out, n,
        (const float*)d_in[2],  (const float*)d_in[3],
        (const float*)d_in[4],  (const float*)d_in[5],
        (const float*)d_in[6],  (const float*)d_in[7],
        (const float*)d_in[8],  (const float*)d_in[9],
        (const float*)d_in[10], (const float*)d_in[11],
        (const float*)d_in[12], (const float*)d_in[13],
        (const float*)d_in[14], (const float*)d_in[15]);
  }
}

// Round 5
// 563.814 us; speedup vs baseline: 7.1428x; 1.3744x over previous
//
#include <hip/hip_runtime.h>
#include <hip/hip_fp16.h>

typedef unsigned int u32;
typedef unsigned short u16;

__device__ __forceinline__ u32 encf(float f){ u32 u=__float_as_uint(f); return (u&0x80000000u)? ~u : (u|0x80000000u); }
__device__ __forceinline__ float decf(u32 u){ return (u&0x80000000u)? __uint_as_float(u&0x7fffffffu) : __uint_as_float(~u); }

__device__ __forceinline__ float fast_tanh(float x){
  x = fminf(fmaxf(x, -15.f), 15.f);
  float e = __expf(2.f*x);
  return (e - 1.f) * __builtin_amdgcn_rcpf(e + 1.f);
}
__device__ __forceinline__ float fast_sigmoid(float x){
  x = fminf(fmaxf(x, -15.f), 15.f);
  return __builtin_amdgcn_rcpf(1.f + __expf(-x));
}

// Base-voxel index, bit-exact with reference: idx = floor(points + 1.0f); ix = idx-1.
__device__ __forceinline__ int base_ix(float p){
  return (int)floorf(p + 1.0f) - 1;   // in [0,254] for p in [0,255)
}

// ---- repack f32 channel-major -> fp16 voxel-major (16B/voxel) + z-dilated ch7
__global__ __launch_bounds__(256) void repack16(const float* __restrict__ g,
                                                uint4* __restrict__ rg,
                                                u16* __restrict__ zd){
  u32 v = blockIdx.x*256u + threadIdx.x;    // 65536 x 256 = 2^24 voxels
  float c0 = g[v];
  float c1 = g[(1u<<24)+v];
  float c2 = g[(2u<<24)+v];
  float c3 = g[(3u<<24)+v];
  float c4 = g[(4u<<24)+v];
  float c5 = g[(5u<<24)+v];
  float c6 = g[(6u<<24)+v];
  float c7 = g[(7u<<24)+v];
  __half2 p0 = __floats2half2_rn(c0,c1);
  __half2 p1 = __floats2half2_rn(c2,c3);
  __half2 p2 = __floats2half2_rn(c4,c5);
  __half2 p3 = __floats2half2_rn(c6,c7);
  uint4 o;
  o.x = *(const u32*)&p0; o.y = *(const u32*)&p1;
  o.z = *(const u32*)&p2; o.w = *(const u32*)&p3;
  rg[v] = o;
  // z-dilation of channel 7 (clamped within the z-row)
  u32 z = v & 255u;
  const float* g7 = g + ((size_t)7u<<24);
  float zm = g7[z==0u   ? v : v-1u];
  float zp = g7[z==255u ? v : v+1u];
  float m = fmaxf(zm, fmaxf(c7, zp));
  zd[v] = __half_as_ushort(__float2half_rn(m));
}

// ---- y-dilation: yd[v] = max over y-1..y+1 of zd ----------------------------
__global__ __launch_bounds__(256) void ydil(const u16* __restrict__ zd,
                                            u16* __restrict__ yd){
  u32 v = blockIdx.x*256u + threadIdx.x;
  u32 y = (v>>8) & 255u;
  float a = __half2float(__ushort_as_half(zd[y==0u   ? v : v-256u]));
  float b = __half2float(__ushort_as_half(zd[v]));
  float c = __half2float(__ushort_as_half(zd[y==255u ? v : v+256u]));
  float m = fmaxf(a, fmaxf(b, c));
  yd[v] = __half_as_ushort(__float2half_rn(m));
}

// ---- x-dilation: xd[v] = max over x-1..x+1 of yd ----------------------------
__global__ __launch_bounds__(256) void xdil(const u16* __restrict__ yd,
                                            u16* __restrict__ xd){
  u32 v = blockIdx.x*256u + threadIdx.x;
  u32 x = v>>16;
  float a = __half2float(__ushort_as_half(yd[x==0u   ? v : v-65536u]));
  float b = __half2float(__ushort_as_half(yd[v]));
  float c = __half2float(__ushort_as_half(yd[x==255u ? v : v+65536u]));
  float m = fmaxf(a, fmaxf(b, c));
  xd[v] = __half_as_ushort(__float2half_rn(m));
}

// ---- per-point max of dilated ch7 (== max over all gathered values) ---------
__global__ __launch_bounds__(256) void kmax_pt(const float* __restrict__ pts,
                                               const u16* __restrict__ xd,
                                               u32* __restrict__ wmax, int n){
  __shared__ float red[4];
  float m = -3.0e38f;
  for (int i = blockIdx.x*blockDim.x + threadIdx.x; i < n; i += gridDim.x*blockDim.x){
    int ix = base_ix(pts[3*i]);
    int iy = base_ix(pts[3*i+1]);
    int iz = base_ix(pts[3*i+2]);
    u32 cb = ((u32)ix<<16) | ((u32)iy<<8) | (u32)iz;
    m = fmaxf(m, __half2float(__ushort_as_half(xd[cb])));
  }
  #pragma unroll
  for (int o=32;o>=1;o>>=1) m = fmaxf(m, __shfl_xor(m, o));
  int wid = threadIdx.x >> 6;
  if ((threadIdx.x & 63)==0) red[wid] = m;
  __syncthreads();
  if (threadIdx.x == 0){
    float r = fmaxf(fmaxf(red[0],red[1]), fmaxf(red[2],red[3]));
    atomicMax(wmax, encf(r));
  }
}

// ================= shared MLP tail ==========================================
__device__ __forceinline__ void mlp_tail(const float* __restrict__ cen,
                                         const float* __restrict__ acc0,
                                         float2* __restrict__ out, int i,
                                         const float* __restrict__ W1, const float* __restrict__ b1,
                                         const float* __restrict__ W2, const float* __restrict__ b2,
                                         const float* __restrict__ W3, const float* __restrict__ b3,
                                         const float* __restrict__ W4, const float* __restrict__ b4,
                                         const float* __restrict__ Ws, const float* __restrict__ bs,
                                         const float* __restrict__ Wo, const float* __restrict__ bo)
{
  float mean = 0.f;
  #pragma unroll
  for (int j=0;j<8;j++) mean += acc0[j];
  mean *= 0.125f;
  float var = 0.f;
  #pragma unroll
  for (int j=0;j<8;j++){ float t = acc0[j]-mean; var += t*t; }
  var *= 0.125f;
  float rs = rsqrtf(var + 1e-5f);
  float ctx[8];
  #pragma unroll
  for (int j=0;j<8;j++) ctx[j] = fast_tanh((acc0[j]-mean)*rs);

  float h1[32];
  #pragma unroll
  for (int j=0;j<32;j++){
    float s = b1[j];
    #pragma unroll
    for (int c=0;c<8;c++) s = fmaf(cen[c], W1[c*32 + j], s);
    #pragma unroll
    for (int c=0;c<8;c++) s = fmaf(ctx[c], W1[(8+c)*32 + j], s);
    h1[j] = fast_tanh(s);
  }
  float h2[16];
  #pragma unroll
  for (int j=0;j<16;j++){
    float s = b2[j];
    #pragma unroll
    for (int c=0;c<8;c++) s = fmaf(cen[c], W2[c*16 + j], s);
    #pragma unroll
    for (int c=0;c<32;c++) s = fmaf(h1[c], W2[(8+c)*16 + j], s);
    h2[j] = fast_tanh(s);
  }
  float h3[8];
  #pragma unroll
  for (int j=0;j<8;j++){
    float s = b3[j];
    #pragma unroll
    for (int c=0;c<8;c++) s = fmaf(cen[c], W3[c*8 + j], s);
    #pragma unroll
    for (int c=0;c<16;c++) s = fmaf(h2[c], W3[(8+c)*8 + j], s);
    h3[j] = fast_tanh(s);
  }
  float h4[8];
  #pragma unroll
  for (int j=0;j<8;j++){
    float s = b4[j];
    #pragma unroll
    for (int c=0;c<8;c++) s = fmaf(cen[c], W4[c*8 + j], s);
    #pragma unroll
    for (int c=0;c<8;c++) s = fmaf(h3[c], W4[(8+c)*8 + j], s);
    h4[j] = fast_tanh(s);
  }
  float ssdf = bs[0];
  float socc = bo[0];
  #pragma unroll
  for (int c=0;c<8;c++){
    ssdf = fmaf(h4[c], Ws[c], ssdf);
    socc = fmaf(h4[c], Wo[c], socc);
  }
  out[i] = make_float2(fast_tanh(ssdf), fast_sigmoid(socc));
}

// ---- pass 2 (fast path): gather from fp16 voxel-major repack ----------------
__global__ __launch_bounds__(256) void kmain16(const float* __restrict__ pts,
                                               const uint4* __restrict__ rg,
                                               const u32* __restrict__ wmax,
                                               float2* __restrict__ out, int n,
                                               const float* __restrict__ Wc, const float* __restrict__ bc,
                                               const float* __restrict__ W1, const float* __restrict__ b1,
                                               const float* __restrict__ W2, const float* __restrict__ b2,
                                               const float* __restrict__ W3, const float* __restrict__ b3,
                                               const float* __restrict__ W4, const float* __restrict__ b4,
                                               const float* __restrict__ Ws, const float* __restrict__ bs,
                                               const float* __restrict__ Wo, const float* __restrict__ bo)
{
  int i = blockIdx.x*256 + threadIdx.x;
  if (i >= n) return;
  float inv = 1.0f / (decf(*wmax) + 1e-9f);

  int ix = base_ix(pts[3*i]);
  int iy = base_ix(pts[3*i+1]);
  int iz = base_ix(pts[3*i+2]);
  int xs[3] = {max(ix-1,0), ix, min(ix+1,255)};
  int ys[3] = {max(iy-1,0), iy, min(iy+1,255)};
  int zs[3] = {max(iz-1,0), iz, min(iz+1,255)};

  float cen[8];
  float acc[8];
  #pragma unroll
  for (int j=0;j<8;j++) acc[j] = bc[j];

  #pragma unroll
  for (int a=0;a<3;a++)
  #pragma unroll
  for (int b=0;b<3;b++)
  #pragma unroll
  for (int d=0;d<3;d++){
    const int kk = (a*3+b)*3+d;
    u32 vb = ((u32)xs[a]<<16) | ((u32)ys[b]<<8) | (u32)zs[d];
    uint4 q = rg[vb];
    float2 f0 = __half22float2(*(const __half2*)&q.x);
    float2 f1 = __half22float2(*(const __half2*)&q.y);
    float2 f2 = __half22float2(*(const __half2*)&q.z);
    float2 f3 = __half22float2(*(const __half2*)&q.w);
    float v[8] = {f0.x,f0.y,f1.x,f1.y,f2.x,f2.y,f3.x, f3.y*inv};
    if (kk == 13){
      #pragma unroll
      for (int c=0;c<8;c++) cen[c] = v[c];
    }
    #pragma unroll
    for (int c=0;c<8;c++)
      #pragma unroll
      for (int j=0;j<8;j++)
        acc[j] = fmaf(v[c], Wc[(kk*8+c)*8 + j], acc[j]);
  }

  mlp_tail(cen, acc, out, i, W1,b1,W2,b2,W3,b3,W4,b4,Ws,bs,Wo,bo);
}

// ---- fallback path (round-3): direct channel-major gather -------------------
__global__ __launch_bounds__(256) void kmax_direct(const float* __restrict__ pts,
                                                   const float* __restrict__ g7,
                                                   u32* __restrict__ wmax, int n){
  float m = -3.0e38f;
  for (int i = blockIdx.x*blockDim.x + threadIdx.x; i < n; i += gridDim.x*blockDim.x){
    int ix = base_ix(pts[3*i]);
    int iy = base_ix(pts[3*i+1]);
    int iz = base_ix(pts[3*i+2]);
    int xs[3] = {max(ix-1,0), ix, min(ix+1,255)};
    int ys[3] = {max(iy-1,0), iy, min(iy+1,255)};
    int zs[3] = {max(iz-1,0), iz, min(iz+1,255)};
    #pragma unroll
    for (int a=0;a<3;a++)
    #pragma unroll
    for (int b=0;b<3;b++){
      u32 rb = ((u32)xs[a]<<16) | ((u32)ys[b]<<8);
      #pragma unroll
      for (int d=0;d<3;d++) m = fmaxf(m, g7[rb + (u32)zs[d]]);
    }
  }
  #pragma unroll
  for (int o=32;o>=1;o>>=1) m = fmaxf(m, __shfl_xor(m, o));
  if ((threadIdx.x & 63)==0) atomicMax(wmax, encf(m));
}

__global__ __launch_bounds__(256) void kmain_direct(const float* __restrict__ pts,
                                                    const float* __restrict__ g,
                                                    const u32* __restrict__ wmax,
                                                    float2* __restrict__ out, int n,
                                                    const float* __restrict__ Wc, const float* __restrict__ bc,
                                                    const float* __restrict__ W1, const float* __restrict__ b1,
                                                    const float* __restrict__ W2, const float* __restrict__ b2,
                                                    const float* __restrict__ W3, const float* __restrict__ b3,
                                                    const float* __restrict__ W4, const float* __restrict__ b4,
                                                    const float* __restrict__ Ws, const float* __restrict__ bs,
                                                    const float* __restrict__ Wo, const float* __restrict__ bo)
{
  int i = blockIdx.x*256 + threadIdx.x;
  if (i >= n) return;
  float inv = 1.0f / (decf(*wmax) + 1e-9f);

  int ix = base_ix(pts[3*i]);
  int iy = base_ix(pts[3*i+1]);
  int iz = base_ix(pts[3*i+2]);
  int xs[3] = {max(ix-1,0), ix, min(ix+1,255)};
  int ys[3] = {max(iy-1,0), iy, min(iy+1,255)};
  int zs[3] = {max(iz-1,0), iz, min(iz+1,255)};

  u32 cb = ((u32)ix<<16) | ((u32)iy<<8) | (u32)iz;
  float cen[8];
  #pragma unroll
  for (int c=0;c<8;c++) cen[c] = g[((u32)c<<24) + cb];
  cen[7] *= inv;

  float acc[8];
  #pragma unroll
  for (int j=0;j<8;j++) acc[j] = bc[j];

  #pragma unroll
  for (int a=0;a<3;a++)
  #pragma unroll
  for (int b=0;b<3;b++)
  #pragma unroll
  for (int d=0;d<3;d++){
    const int kk = (a*3+b)*3+d;
    u32 vb = ((u32)xs[a]<<16) | ((u32)ys[b]<<8) | (u32)zs[d];
    float v[8];
    #pragma unroll
    for (int c=0;c<8;c++) v[c] = g[((u32)c<<24) + vb];
    v[7] *= inv;
    #pragma unroll
    for (int c=0;c<8;c++)
      #pragma unroll
      for (int j=0;j<8;j++)
        acc[j] = fmaf(v[c], Wc[(kk*8+c)*8 + j], acc[j]);
  }

  mlp_tail(cen, acc, out, i, W1,b1,W2,b2,W3,b3,W4,b4,Ws,bs,Wo,bo);
}

extern "C" void kernel_launch(void* const* d_in, const int* in_sizes, int n_in,
                              void* d_out, int out_size, void* d_ws, size_t ws_size,
                              hipStream_t stream)
{
  const float* pts  = (const float*)d_in[0];
  const float* grid = (const float*)d_in[1];
  int n = in_sizes[0] / 3;

  const size_t NV       = (size_t)1 << 24;
  const size_t RG_BYTES = NV * 16;          // 256 MiB fp16 voxel-major
  const size_t SL_BYTES = NV * 2;           // 32 MiB per dilation slab
  const size_t NEED     = RG_BYTES + 3*SL_BYTES + 64;

  if (ws_size >= NEED){
    char* base = (char*)d_ws;
    uint4* rg  = (uint4*)base;
    u16*   zd  = (u16*)(base + RG_BYTES);
    u16*   yd  = (u16*)(base + RG_BYTES + SL_BYTES);
    u16*   xd  = (u16*)(base + RG_BYTES + 2*SL_BYTES);
    u32*   wmax= (u32*)(base + RG_BYTES + 3*SL_BYTES);

    hipMemsetAsync(wmax, 0, 64, stream);
    repack16<<<65536, 256, 0, stream>>>(grid, rg, zd);
    ydil<<<65536, 256, 0, stream>>>(zd, yd);
    xdil<<<65536, 256, 0, stream>>>(yd, xd);
    kmax_pt<<<2048, 256, 0, stream>>>(pts, xd, wmax, n);
    kmain16<<<(n+255)/256, 256, 0, stream>>>(pts, rg, wmax, (float2*)d_out, n,
        (const float*)d_in[2],  (const float*)d_in[3],
        (const float*)d_in[4],  (const float*)d_in[5],
        (const float*)d_in[6],  (const float*)d_in[7],
        (const float*)d_in[8],  (const float*)d_in[9],
        (const float*)d_in[10], (const float*)d_in[11],
        (const float*)d_in[12], (const float*)d_in[13],
        (const float*)d_in[14], (const float*)d_in[15]);
  } else {
    u32* wmax = (u32*)d_ws;
    hipMemsetAsync(wmax, 0, 64, stream);
    kmax_direct<<<2048, 256, 0, stream>>>(pts, grid + ((size_t)7<<24), wmax, n);
    kmain_direct<<<(n+255)/256, 256, 0, stream>>>(pts, grid, wmax, (float2*)d_out, n,
        (const float*)d_in[2],  (const float*)d_in[3],
        (const float*)d_in[4],  (const float*)d_in[5],
        (const float*)d_in[6],  (const float*)d_in[7],
        (const float*)d_in[8],  (const float*)d_in[9],
        (const float*)d_in[10], (const float*)d_in[11],
        (const float*)d_in[12], (const float*)d_in[13],
        (const float*)d_in[14], (const float*)d_in[15]);
  }
}

// Round 6
// 541.696 us; speedup vs baseline: 7.4344x; 1.0408x over previous
//
#include <hip/hip_runtime.h>
#include <hip/hip_fp16.h>

typedef unsigned int u32;
typedef unsigned short u16;

__device__ __forceinline__ u32 encf(float f){ u32 u=__float_as_uint(f); return (u&0x80000000u)? ~u : (u|0x80000000u); }
__device__ __forceinline__ float decf(u32 u){ return (u&0x80000000u)? __uint_as_float(u&0x7fffffffu) : __uint_as_float(~u); }

__device__ __forceinline__ float fast_tanh(float x){
  x = fminf(fmaxf(x, -15.f), 15.f);
  float e = __expf(2.f*x);
  return (e - 1.f) * __builtin_amdgcn_rcpf(e + 1.f);
}
__device__ __forceinline__ float fast_sigmoid(float x){
  x = fminf(fmaxf(x, -15.f), 15.f);
  return __builtin_amdgcn_rcpf(1.f + __expf(-x));
}

// Base-voxel index, bit-exact with reference: idx = floor(points + 1.0f); ix = idx-1.
__device__ __forceinline__ int base_ix(float p){
  return (int)floorf(p + 1.0f) - 1;   // in [0,254] for p in [0,255)
}

// ---- repack f32 channel-major -> fp16 voxel-major (16B/voxel) ---------------
// Also emits ch7 dilated over (y±1, z±1) — the extra 8 g7 reads are L1-adjacent.
__global__ __launch_bounds__(256) void repack16(const float* __restrict__ g,
                                                uint4* __restrict__ rg,
                                                u16* __restrict__ zy){
  u32 v = blockIdx.x*256u + threadIdx.x;    // 65536 x 256 = 2^24 voxels
  float c0 = g[v];
  float c1 = g[(1u<<24)+v];
  float c2 = g[(2u<<24)+v];
  float c3 = g[(3u<<24)+v];
  float c4 = g[(4u<<24)+v];
  float c5 = g[(5u<<24)+v];
  float c6 = g[(6u<<24)+v];
  float c7 = g[(7u<<24)+v];
  __half2 p0 = __floats2half2_rn(c0,c1);
  __half2 p1 = __floats2half2_rn(c2,c3);
  __half2 p2 = __floats2half2_rn(c4,c5);
  __half2 p3 = __floats2half2_rn(c6,c7);
  uint4 o;
  o.x = *(const u32*)&p0; o.y = *(const u32*)&p1;
  o.z = *(const u32*)&p2; o.w = *(const u32*)&p3;
  rg[v] = o;
  // (y,z)-dilation of channel 7, per-axis clamp
  u32 z = v & 255u;
  u32 y = (v>>8) & 255u;
  const float* g7 = g + ((size_t)7u<<24);
  u32 zm = (z==0u)? v : v-1u;
  u32 zp = (z==255u)? v : v+1u;
  float m = -3.0e38f;
  #pragma unroll
  for (int dy=-1; dy<=1; ++dy){
    int yy = (int)y + dy;
    u32 ro = (yy<0 || yy>255) ? 0u : (u32)(dy*256);
    u32 b0 = zm + ro, b1 = v + ro, b2 = zp + ro;
    m = fmaxf(m, fmaxf(g7[b0], fmaxf(g7[b1], g7[b2])));
  }
  zy[v] = __half_as_ushort(__float2half_rn(m));
}

// ---- x-dilation: xd[v] = max over x-1..x+1 of zy ----------------------------
__global__ __launch_bounds__(256) void xdil(const u16* __restrict__ zy,
                                            u16* __restrict__ xd){
  u32 v = blockIdx.x*256u + threadIdx.x;
  u32 x = v>>16;
  float a = __half2float(__ushort_as_half(zy[x==0u   ? v : v-65536u]));
  float b = __half2float(__ushort_as_half(zy[v]));
  float c = __half2float(__ushort_as_half(zy[x==255u ? v : v+65536u]));
  float m = fmaxf(a, fmaxf(b, c));
  xd[v] = __half_as_ushort(__float2half_rn(m));
}

// ---- counting sort by 8^3-voxel cell (32768 cells) --------------------------
__device__ __forceinline__ u32 cell_id(int ix, int iy, int iz){
  return ((u32)(ix>>3)<<10) | ((u32)(iy>>3)<<5) | (u32)(iz>>3);
}

__global__ __launch_bounds__(256) void hist(const float* __restrict__ pts,
                                            u32* __restrict__ cnt, int n){
  for (int i = blockIdx.x*blockDim.x + threadIdx.x; i < n; i += gridDim.x*blockDim.x){
    int ix = base_ix(pts[3*i]);
    int iy = base_ix(pts[3*i+1]);
    int iz = base_ix(pts[3*i+2]);
    atomicAdd(&cnt[cell_id(ix,iy,iz)], 1u);
  }
}

// one-block exclusive scan of 32768 = 1024 x 32
__global__ __launch_bounds__(1024) void scan32k(const u32* __restrict__ cnt,
                                                u32* __restrict__ ofs){
  __shared__ u32 sums[1024];
  int t = threadIdx.x;
  u32 loc[32];
  u32 s = 0;
  #pragma unroll
  for (int k=0;k<32;k++){ loc[k] = cnt[t*32+k]; s += loc[k]; }
  sums[t] = s;
  __syncthreads();
  for (int off=1; off<1024; off<<=1){
    u32 v = (t>=off)? sums[t-off] : 0u;
    __syncthreads();
    sums[t] += v;
    __syncthreads();
  }
  u32 run = (t>0)? sums[t-1] : 0u;
  #pragma unroll
  for (int k=0;k<32;k++){ ofs[t*32+k] = run; run += loc[k]; }
}

__global__ __launch_bounds__(256) void scatter(const float* __restrict__ pts,
                                               u32* __restrict__ ofs,
                                               float4* __restrict__ srt, int n){
  for (int i = blockIdx.x*blockDim.x + threadIdx.x; i < n; i += gridDim.x*blockDim.x){
    float px = pts[3*i], py = pts[3*i+1], pz = pts[3*i+2];
    int ix = base_ix(px), iy = base_ix(py), iz = base_ix(pz);
    u32 r = atomicAdd(&ofs[cell_id(ix,iy,iz)], 1u);
    srt[r] = make_float4(px, py, pz, __uint_as_float((u32)i));
  }
}

// ---- per-point max of dilated ch7 (== max over all gathered values) ---------
__global__ __launch_bounds__(256) void kmax_pt(const float4* __restrict__ srt,
                                               const u16* __restrict__ xd,
                                               u32* __restrict__ wmax, int n){
  __shared__ float red[4];
  float m = -3.0e38f;
  for (int i = blockIdx.x*blockDim.x + threadIdx.x; i < n; i += gridDim.x*blockDim.x){
    float4 rec = srt[i];
    int ix = base_ix(rec.x);
    int iy = base_ix(rec.y);
    int iz = base_ix(rec.z);
    u32 cb = ((u32)ix<<16) | ((u32)iy<<8) | (u32)iz;
    m = fmaxf(m, __half2float(__ushort_as_half(xd[cb])));
  }
  #pragma unroll
  for (int o=32;o>=1;o>>=1) m = fmaxf(m, __shfl_xor(m, o));
  int wid = threadIdx.x >> 6;
  if ((threadIdx.x & 63)==0) red[wid] = m;
  __syncthreads();
  if (threadIdx.x == 0){
    float r = fmaxf(fmaxf(red[0],red[1]), fmaxf(red[2],red[3]));
    atomicMax(wmax, encf(r));
  }
}

// ================= shared MLP tail ==========================================
__device__ __forceinline__ void mlp_tail(const float* __restrict__ cen,
                                         const float* __restrict__ acc0,
                                         float2* __restrict__ out, int i,
                                         const float* __restrict__ W1, const float* __restrict__ b1,
                                         const float* __restrict__ W2, const float* __restrict__ b2,
                                         const float* __restrict__ W3, const float* __restrict__ b3,
                                         const float* __restrict__ W4, const float* __restrict__ b4,
                                         const float* __restrict__ Ws, const float* __restrict__ bs,
                                         const float* __restrict__ Wo, const float* __restrict__ bo)
{
  float mean = 0.f;
  #pragma unroll
  for (int j=0;j<8;j++) mean += acc0[j];
  mean *= 0.125f;
  float var = 0.f;
  #pragma unroll
  for (int j=0;j<8;j++){ float t = acc0[j]-mean; var += t*t; }
  var *= 0.125f;
  float rs = rsqrtf(var + 1e-5f);
  float ctx[8];
  #pragma unroll
  for (int j=0;j<8;j++) ctx[j] = fast_tanh((acc0[j]-mean)*rs);

  float h1[32];
  #pragma unroll
  for (int j=0;j<32;j++){
    float s = b1[j];
    #pragma unroll
    for (int c=0;c<8;c++) s = fmaf(cen[c], W1[c*32 + j], s);
    #pragma unroll
    for (int c=0;c<8;c++) s = fmaf(ctx[c], W1[(8+c)*32 + j], s);
    h1[j] = fast_tanh(s);
  }
  float h2[16];
  #pragma unroll
  for (int j=0;j<16;j++){
    float s = b2[j];
    #pragma unroll
    for (int c=0;c<8;c++) s = fmaf(cen[c], W2[c*16 + j], s);
    #pragma unroll
    for (int c=0;c<32;c++) s = fmaf(h1[c], W2[(8+c)*16 + j], s);
    h2[j] = fast_tanh(s);
  }
  float h3[8];
  #pragma unroll
  for (int j=0;j<8;j++){
    float s = b3[j];
    #pragma unroll
    for (int c=0;c<8;c++) s = fmaf(cen[c], W3[c*8 + j], s);
    #pragma unroll
    for (int c=0;c<16;c++) s = fmaf(h2[c], W3[(8+c)*8 + j], s);
    h3[j] = fast_tanh(s);
  }
  float h4[8];
  #pragma unroll
  for (int j=0;j<8;j++){
    float s = b4[j];
    #pragma unroll
    for (int c=0;c<8;c++) s = fmaf(cen[c], W4[c*8 + j], s);
    #pragma unroll
    for (int c=0;c<8;c++) s = fmaf(h3[c], W4[(8+c)*8 + j], s);
    h4[j] = fast_tanh(s);
  }
  float ssdf = bs[0];
  float socc = bo[0];
  #pragma unroll
  for (int c=0;c<8;c++){
    ssdf = fmaf(h4[c], Ws[c], ssdf);
    socc = fmaf(h4[c], Wo[c], socc);
  }
  out[i] = make_float2(fast_tanh(ssdf), fast_sigmoid(socc));
}

// ---- pass 2 (fast path): sorted points, fp16 voxel-major gather -------------
__global__ __launch_bounds__(256) void kmain16(const float4* __restrict__ srt,
                                               const uint4* __restrict__ rg,
                                               const u32* __restrict__ wmax,
                                               float2* __restrict__ out, int n,
                                               const float* __restrict__ Wc, const float* __restrict__ bc,
                                               const float* __restrict__ W1, const float* __restrict__ b1,
                                               const float* __restrict__ W2, const float* __restrict__ b2,
                                               const float* __restrict__ W3, const float* __restrict__ b3,
                                               const float* __restrict__ W4, const float* __restrict__ b4,
                                               const float* __restrict__ Ws, const float* __restrict__ bs,
                                               const float* __restrict__ Wo, const float* __restrict__ bo)
{
  // bijective XCD swizzle: consecutive sorted blocks -> same XCD L2
  u32 nwg = gridDim.x;
  u32 q = nwg >> 3, r = nwg & 7u;
  u32 xcd = blockIdx.x & 7u, sub = blockIdx.x >> 3;
  u32 bid = (xcd < r ? xcd*(q+1u) : r*(q+1u) + (xcd-r)*q) + sub;

  int j = (int)(bid*256u + threadIdx.x);
  if (j >= n) return;
  float4 rec = srt[j];
  int i = (int)__float_as_uint(rec.w);
  float inv = 1.0f / (decf(*wmax) + 1e-9f);

  int ix = base_ix(rec.x);
  int iy = base_ix(rec.y);
  int iz = base_ix(rec.z);
  int xs[3] = {max(ix-1,0), ix, min(ix+1,255)};
  int ys[3] = {max(iy-1,0), iy, min(iy+1,255)};
  int zs[3] = {max(iz-1,0), iz, min(iz+1,255)};

  float cen[8];
  float acc[8];
  #pragma unroll
  for (int jj=0;jj<8;jj++) acc[jj] = bc[jj];

  #pragma unroll
  for (int a=0;a<3;a++)
  #pragma unroll
  for (int b=0;b<3;b++)
  #pragma unroll
  for (int d=0;d<3;d++){
    const int kk = (a*3+b)*3+d;
    u32 vb = ((u32)xs[a]<<16) | ((u32)ys[b]<<8) | (u32)zs[d];
    uint4 qv = rg[vb];
    float2 f0 = __half22float2(*(const __half2*)&qv.x);
    float2 f1 = __half22float2(*(const __half2*)&qv.y);
    float2 f2 = __half22float2(*(const __half2*)&qv.z);
    float2 f3 = __half22float2(*(const __half2*)&qv.w);
    float v[8] = {f0.x,f0.y,f1.x,f1.y,f2.x,f2.y,f3.x, f3.y*inv};
    if (kk == 13){
      #pragma unroll
      for (int c=0;c<8;c++) cen[c] = v[c];
    }
    #pragma unroll
    for (int c=0;c<8;c++)
      #pragma unroll
      for (int jj=0;jj<8;jj++)
        acc[jj] = fmaf(v[c], Wc[(kk*8+c)*8 + jj], acc[jj]);
  }

  mlp_tail(cen, acc, out, i, W1,b1,W2,b2,W3,b3,W4,b4,Ws,bs,Wo,bo);
}

// ---- fallback path (round-3): direct channel-major gather -------------------
__global__ __launch_bounds__(256) void kmax_direct(const float* __restrict__ pts,
                                                   const float* __restrict__ g7,
                                                   u32* __restrict__ wmax, int n){
  float m = -3.0e38f;
  for (int i = blockIdx.x*blockDim.x + threadIdx.x; i < n; i += gridDim.x*blockDim.x){
    int ix = base_ix(pts[3*i]);
    int iy = base_ix(pts[3*i+1]);
    int iz = base_ix(pts[3*i+2]);
    int xs[3] = {max(ix-1,0), ix, min(ix+1,255)};
    int ys[3] = {max(iy-1,0), iy, min(iy+1,255)};
    int zs[3] = {max(iz-1,0), iz, min(iz+1,255)};
    #pragma unroll
    for (int a=0;a<3;a++)
    #pragma unroll
    for (int b=0;b<3;b++){
      u32 rb = ((u32)xs[a]<<16) | ((u32)ys[b]<<8);
      #pragma unroll
      for (int d=0;d<3;d++) m = fmaxf(m, g7[rb + (u32)zs[d]]);
    }
  }
  #pragma unroll
  for (int o=32;o>=1;o>>=1) m = fmaxf(m, __shfl_xor(m, o));
  if ((threadIdx.x & 63)==0) atomicMax(wmax, encf(m));
}

__global__ __launch_bounds__(256) void kmain_direct(const float* __restrict__ pts,
                                                    const float* __restrict__ g,
                                                    const u32* __restrict__ wmax,
                                                    float2* __restrict__ out, int n,
                                                    const float* __restrict__ Wc, const float* __restrict__ bc,
                                                    const float* __restrict__ W1, const float* __restrict__ b1,
                                                    const float* __restrict__ W2, const float* __restrict__ b2,
                                                    const float* __restrict__ W3, const float* __restrict__ b3,
                                                    const float* __restrict__ W4, const float* __restrict__ b4,
                                                    const float* __restrict__ Ws, const float* __restrict__ bs,
                                                    const float* __restrict__ Wo, const float* __restrict__ bo)
{
  int i = blockIdx.x*256 + threadIdx.x;
  if (i >= n) return;
  float inv = 1.0f / (decf(*wmax) + 1e-9f);

  int ix = base_ix(pts[3*i]);
  int iy = base_ix(pts[3*i+1]);
  int iz = base_ix(pts[3*i+2]);
  int xs[3] = {max(ix-1,0), ix, min(ix+1,255)};
  int ys[3] = {max(iy-1,0), iy, min(iy+1,255)};
  int zs[3] = {max(iz-1,0), iz, min(iz+1,255)};

  u32 cb = ((u32)ix<<16) | ((u32)iy<<8) | (u32)iz;
  float cen[8];
  #pragma unroll
  for (int c=0;c<8;c++) cen[c] = g[((u32)c<<24) + cb];
  cen[7] *= inv;

  float acc[8];
  #pragma unroll
  for (int j=0;j<8;j++) acc[j] = bc[j];

  #pragma unroll
  for (int a=0;a<3;a++)
  #pragma unroll
  for (int b=0;b<3;b++)
  #pragma unroll
  for (int d=0;d<3;d++){
    const int kk = (a*3+b)*3+d;
    u32 vb = ((u32)xs[a]<<16) | ((u32)ys[b]<<8) | (u32)zs[d];
    float v[8];
    #pragma unroll
    for (int c=0;c<8;c++) v[c] = g[((u32)c<<24) + vb];
    v[7] *= inv;
    #pragma unroll
    for (int c=0;c<8;c++)
      #pragma unroll
      for (int j=0;j<8;j++)
        acc[j] = fmaf(v[c], Wc[(kk*8+c)*8 + j], acc[j]);
  }

  mlp_tail(cen, acc, out, i, W1,b1,W2,b2,W3,b3,W4,b4,Ws,bs,Wo,bo);
}

extern "C" void kernel_launch(void* const* d_in, const int* in_sizes, int n_in,
                              void* d_out, int out_size, void* d_ws, size_t ws_size,
                              hipStream_t stream)
{
  const float* pts  = (const float*)d_in[0];
  const float* grid = (const float*)d_in[1];
  int n = in_sizes[0] / 3;

  const size_t NV       = (size_t)1 << 24;
  const size_t RG_BYTES = NV * 16;                   // 256 MiB fp16 voxel-major
  const size_t SL_BYTES = NV * 2;                    // 32 MiB per dilation slab
  const size_t SRT_BYTES= (size_t)n * 16;            // 16 MiB sorted records
  const size_t CNT_BYTES= 32768 * 4;
  const size_t NEED     = RG_BYTES + 2*SL_BYTES + SRT_BYTES + 2*CNT_BYTES + 64;

  if (ws_size >= NEED){
    char* base = (char*)d_ws;
    uint4*  rg   = (uint4*)base;
    u16*    zy   = (u16*)(base + RG_BYTES);
    u16*    xd   = (u16*)(base + RG_BYTES + SL_BYTES);
    float4* srt  = (float4*)(base + RG_BYTES + 2*SL_BYTES);
    u32*    cnt  = (u32*)(base + RG_BYTES + 2*SL_BYTES + SRT_BYTES);
    u32*    ofs  = (u32*)(base + RG_BYTES + 2*SL_BYTES + SRT_BYTES + CNT_BYTES);
    u32*    wmax = (u32*)(base + RG_BYTES + 2*SL_BYTES + SRT_BYTES + 2*CNT_BYTES);

    hipMemsetAsync(cnt, 0, CNT_BYTES, stream);
    hipMemsetAsync(wmax, 0, 64, stream);
    repack16<<<65536, 256, 0, stream>>>(grid, rg, zy);
    xdil<<<65536, 256, 0, stream>>>(zy, xd);
    hist<<<2048, 256, 0, stream>>>(pts, cnt, n);
    scan32k<<<1, 1024, 0, stream>>>(cnt, ofs);
    scatter<<<2048, 256, 0, stream>>>(pts, ofs, srt, n);
    kmax_pt<<<2048, 256, 0, stream>>>(srt, xd, wmax, n);
    kmain16<<<(n+255)/256, 256, 0, stream>>>(srt, rg, wmax, (float2*)d_out, n,
        (const float*)d_in[2],  (const float*)d_in[3],
        (const float*)d_in[4],  (const float*)d_in[5],
        (const float*)d_in[6],  (const float*)d_in[7],
        (const float*)d_in[8],  (const float*)d_in[9],
        (const float*)d_in[10], (const float*)d_in[11],
        (const float*)d_in[12], (const float*)d_in[13],
        (const float*)d_in[14], (const float*)d_in[15]);
  } else {
    u32* wmax = (u32*)d_ws;
    hipMemsetAsync(wmax, 0, 64, stream);
    kmax_direct<<<2048, 256, 0, stream>>>(pts, grid + ((size_t)7<<24), wmax, n);
    kmain_direct<<<(n+255)/256, 256, 0, stream>>>(pts, grid, wmax, (float2*)d_out, n,
        (const float*)d_in[2],  (const float*)d_in[3],
        (const float*)d_in[4],  (const float*)d_in[5],
        (const float*)d_in[6],  (const float*)d_in[7],
        (const float*)d_in[8],  (const float*)d_in[9],
        (const float*)d_in[10], (const float*)d_in[11],
        (const float*)d_in[12], (const float*)d_in[13],
        (const float*)d_in[14], (const float*)d_in[15]);
  }
}